// Round 4
// baseline (166.980 us; speedup 1.0000x reference)
//
#include <hip/hip_runtime.h>
#include <cmath>

#define N_ 32
#define B_ 64
#define T_ 8192
#define CPB 16                      // 512-t slices per b
#define PSTRIDE 2176                // 1024 pp + 1024 pn + 4*32 sums
// LDS: per tensor, 16 row-pairs; pair = 2 rows x 512 B (128 fp32) + 16 B shim.
// Pair pitch 1040 B = 260 dwords -> 4-dword bank shift per pair -> 2-way conflicts (free).
#define PAIRF 260                   // pair pitch in floats
#define TENSF 4160                  // 16 * PAIRF, tensor region in floats
#define LDSB  33280                 // 2 * TENSF * 4 bytes

typedef _Float16 half8 __attribute__((ext_vector_type(8)));
typedef float floatx4 __attribute__((ext_vector_type(4)));

// ---------------- Stage 1: DMA (global_load_lds) -> fp32 LDS -> cvt+MFMA ----------------
// grid 1024 = 64 b * 16 slices (512 t); block 512 (8 waves) -> 4 blocks/CU.
// Pearson is invariant to the reference's per-n affine normalization -> raw data.
// Staging uses global_load_lds width=16: no payload VGPRs, ~128 KB in flight per CU.
// Each wave owns ONE 16x16 quadrant of ONE Gram (pp or pn): 4 acc VGPRs, direct store.
__global__ __launch_bounds__(512, 8) void k_stage1(const float* __restrict__ pos,
                                                   const float* __restrict__ neg,
                                                   float* __restrict__ partial) {
    __shared__ __align__(16) float smem[LDSB / 4];

    const int bid = blockIdx.x;
    const int b = bid >> 4, c = bid & 15;
    const int tid = threadIdx.x;
    const int wave = tid >> 6, lane = tid & 63;

    // --- DMA role: wave w stages 4 pairs of tensor (w>>2); pair p = (w&3)*4 + j ---
    const int tzw = wave >> 2;
    const int quad = wave & 3;
    const float* gsrc = tzw ? neg : pos;
    const float* gptr[4];
    int ldsoff[4];   // float offset, wave-uniform
#pragma unroll
    for (int j = 0; j < 4; ++j) {
        int p = quad * 4 + j;
        int row = 2 * p + (lane >> 5);            // Gram row staged by this half-wave
        gptr[j] = gsrc + ((long)(row * B_ + b)) * T_ + c * 512 + (lane & 31) * 4;
        ldsoff[j] = tzw * TENSF + p * PAIRF;
    }

    // --- MFMA role: quadrant (qi,qj) of Gram `mat` ---
    const int mat = wave >> 2, qi = (wave >> 1) & 1, qj = wave & 1;
    const int m16 = lane & 15, h2 = lane >> 4;    // 0..15, 0..3
    const int arow = qi * 16 + m16, brow = qj * 16 + m16;
    const float* aptr = smem + ((arow >> 1) * PAIRF + (arow & 1) * 128);
    const float* bptr = smem + mat * TENSF + ((brow >> 1) * PAIRF + (brow & 1) * 128);

    // --- stats role: 8 threads per (tensor,row) stream ---
    const int stream = tid >> 3, sub = tid & 7;
    const int srow = stream & 31, stz = stream >> 5;
    const float* sptr = smem + stz * TENSF + ((srow >> 1) * PAIRF + (srow & 1) * 128) + sub * 16;

    floatx4 acc = {};
    float ssum = 0.f, ssq = 0.f;

    for (int ch = 0; ch < 4; ++ch) {   // 4 chunks of 128 t
#pragma unroll
        for (int j = 0; j < 4; ++j) {
            __builtin_amdgcn_global_load_lds(
                (const __attribute__((address_space(1))) void*)(gptr[j] + ch * 128),
                (__attribute__((address_space(3))) void*)(smem + ldsoff[j]), 16, 0, 0);
        }
        asm volatile("s_waitcnt vmcnt(0)" ::: "memory");
        __syncthreads();   // chunk staged

        // MFMA: 4 k-steps of 32 (fp32 read -> f16 cvt -> 16x16x32)
        // A-operand layout (m120-verified): A[m = lane&15][k = (lane>>4)*8 + j];
        // same layout both sides -> mfma(x,y) = X . Y^T.
#pragma unroll
        for (int kk = 0; kk < 4; ++kk) {
            const int t0 = kk * 32 + h2 * 8;
            float4 a0 = *(const float4*)(aptr + t0);
            float4 a1 = *(const float4*)(aptr + t0 + 4);
            float4 b0 = *(const float4*)(bptr + t0);
            float4 b1 = *(const float4*)(bptr + t0 + 4);
            half8 af = {(_Float16)a0.x, (_Float16)a0.y, (_Float16)a0.z, (_Float16)a0.w,
                        (_Float16)a1.x, (_Float16)a1.y, (_Float16)a1.z, (_Float16)a1.w};
            half8 bf = {(_Float16)b0.x, (_Float16)b0.y, (_Float16)b0.z, (_Float16)b0.w,
                        (_Float16)b1.x, (_Float16)b1.y, (_Float16)b1.z, (_Float16)b1.w};
            acc = __builtin_amdgcn_mfma_f32_16x16x32_f16(af, bf, acc, 0, 0, 0);
        }

        // stats: this thread's 16 floats of its row-stream
#pragma unroll
        for (int f = 0; f < 4; ++f) {
            float4 v = *(const float4*)(sptr + f * 4);
            ssum += v.x + v.y + v.z + v.w;
            ssq = fmaf(v.x, v.x, ssq); ssq = fmaf(v.y, v.y, ssq);
            ssq = fmaf(v.z, v.z, ssq); ssq = fmaf(v.w, v.w, ssq);
        }

        __syncthreads();   // all reads done before next chunk's DMA overwrites
    }

    // reduce stats across the 8 subs of each stream (same wave: sub = tid&7)
    ssum += __shfl_xor(ssum, 1); ssum += __shfl_xor(ssum, 2); ssum += __shfl_xor(ssum, 4);
    ssq += __shfl_xor(ssq, 1); ssq += __shfl_xor(ssq, 2); ssq += __shfl_xor(ssq, 4);

    float* out = partial + (long)bid * PSTRIDE;
    if (sub == 0) out[2048 + (stz * 2 + 0) * 32 + srow] = ssum;   // sx / sy
    if (sub == 1) out[2048 + (stz * 2 + 1) * 32 + srow] = ssq;    // sx2 / sy2

    // C/D layout 16x16 (m89-verified): col = lane&15, row = (lane>>4)*4 + reg
#pragma unroll
    for (int reg = 0; reg < 4; ++reg) {
        int rr = qi * 16 + h2 * 4 + reg;
        int cc = qj * 16 + m16;
        out[mat * 1024 + rr * 32 + cc] = acc[reg];
    }
}

// ---------------- Stage 2: reduce 16 chunk partials -> per-b stats ----------------
__global__ void k_reduce(const float* __restrict__ partial, float* __restrict__ red) {
    const int b = blockIdx.y;
    const int o = blockIdx.x * 128 + threadIdx.x;   // 0..2175
    const float* in = partial + (long)b * CPB * PSTRIDE;
    float s = 0.f;
#pragma unroll
    for (int c = 0; c < CPB; ++c) s += in[c * PSTRIDE + o];
    red[(long)b * PSTRIDE + o] = s;
}

// ---------------- Stage 3: per-entry pearson over b, exp terms ----------------
__global__ void k_entries(const float* __restrict__ red, double* __restrict__ blocksums) {
    const int tid = threadIdx.x;
    const int w = tid >> 6, lane = tid & 63;
    const int entry = blockIdx.x * 4 + w;
    const int mat = entry >> 10;       // 0 = pp, 1 = pn
    const int idx = entry & 1023;
    const int n = idx >> 5, m = idx & 31;

    const float* rb = red + (long)lane * PSTRIDE;
    float g = rb[mat * 1024 + idx];
    float sxn = rb[2048 + n];
    float sx2n = rb[2080 + n];
    float sym, sy2m;
    if (mat == 0) {
        sym = rb[2048 + m];
        sy2m = rb[2080 + m];
    } else {
        sym = rb[2112 + m];
        sy2m = rb[2144 + m];
    }

    double num = (double)T_ * (double)g - (double)sxn * (double)sym;
    double vx = (double)T_ * (double)sx2n - (double)sxn * (double)sxn;
    double vy = (double)T_ * (double)sy2m - (double)sym * (double)sym;
    double contrib = 1.0 - num / sqrt(vx * vy);

#pragma unroll
    for (int off = 32; off; off >>= 1) contrib += __shfl_down(contrib, off);

    __shared__ double s_pos[4], s_neg[4];
    if (lane == 0) {
        double d = contrib * (1.0 / B_);
        double term = exp(d / 0.08);
        double p = 0.0, q = 0.0;
        if (mat == 0) {
            if (n < m) p = term;     // strict upper triangle only
        } else {
            q = term;
        }
        s_pos[w] = p;
        s_neg[w] = q;
    }
    __syncthreads();
    if (tid == 0) {
        blocksums[blockIdx.x * 2 + 0] = s_pos[0] + s_pos[1] + s_pos[2] + s_pos[3];
        blocksums[blockIdx.x * 2 + 1] = s_neg[0] + s_neg[1] + s_neg[2] + s_neg[3];
    }
}

// ---------------- Stage 4: final scalar ----------------
__global__ void k_final(const double* __restrict__ blocksums, float* __restrict__ out) {
    __shared__ double sp[256], sn[256];
    const int tid = threadIdx.x;
    double p = 0.0, q = 0.0;
    for (int i = tid; i < 512; i += 256) {
        p += blocksums[2 * i + 0];
        q += blocksums[2 * i + 1];
    }
    sp[tid] = p;
    sn[tid] = q;
    __syncthreads();
    for (int s = 128; s; s >>= 1) {
        if (tid < s) {
            sp[tid] += sp[tid + s];
            sn[tid] += sn[tid + s];
        }
        __syncthreads();
    }
    if (tid == 0) out[0] = (float)log10(sp[0] / sn[0] + 1.0);
}

extern "C" void kernel_launch(void* const* d_in, const int* in_sizes, int n_in,
                              void* d_out, int out_size, void* d_ws, size_t ws_size,
                              hipStream_t stream) {
    const float* pos = (const float*)d_in[0];
    const float* neg = (const float*)d_in[1];
    float* out = (float*)d_out;

    char* ws = (char*)d_ws;
    float* partial = (float*)ws;                               // 1024*2176*4 = 8,912,896 B
    float* red = (float*)(ws + (size_t)1024 * PSTRIDE * 4);    //   64*2176*4 =   557,056 B
    double* blocksums = (double*)(ws + (size_t)1024 * PSTRIDE * 4 + (size_t)64 * PSTRIDE * 4);

    k_stage1<<<1024, 512, 0, stream>>>(pos, neg, partial);
    k_reduce<<<dim3(17, 64), 128, 0, stream>>>(partial, red);
    k_entries<<<512, 256, 0, stream>>>(red, blocksums);
    k_final<<<1, 256, 0, stream>>>(blocksums, out);
}

// Round 5
// 161.924 us; speedup vs baseline: 1.0312x; 1.0312x over previous
//
#include <hip/hip_runtime.h>
#include <cmath>

#define N_ 32
#define B_ 64
#define T_ 8192
#define SLICES 8                    // 1024-t slices per b
#define NCH 8                       // 128-t chunks per slice
#define PSTRIDE 2176                // 1024 pp + 1024 pn + 4*32 sums
// LDS: double buffer; buffer = 2 tensors x 16 pairs x 256 floats (pair = 2 rows x 128 t).
// Bank safety via XOR swizzle of 16-B t-slots: slot_phys = slot ^ (row & 7).
#define BUFF 8192                   // floats per buffer (32 KB)

typedef _Float16 half8 __attribute__((ext_vector_type(8)));
typedef float floatx4 __attribute__((ext_vector_type(4)));

// ---------------- Stage 1: pipelined DMA -> fp32 LDS -> cvt+MFMA (+reg stats) ----------
// grid 512 = 64 b * 8 slices; block 512 (8 waves); 64 KB LDS -> exactly 2 blocks/CU.
// Pearson is invariant to the reference's per-n affine normalization -> raw data.
// global_load_lds width=16 keeps chunk ch+1 in flight while chunk ch is consumed
// (raw s_barrier + s_waitcnt vmcnt(4): no compiler vmcnt(0) drain).
// Each wave owns ONE 16x16 quadrant of ONE Gram; stats accumulate inside the MFMA
// waves from the same fp32 LDS reads (no separate stats reads -> no conflicts).
__global__ __launch_bounds__(512, 4) void k_stage1(const float* __restrict__ pos,
                                                   const float* __restrict__ neg,
                                                   float* __restrict__ partial) {
    __shared__ __align__(16) float smem[2 * BUFF];   // 65536 B

    const int bid = blockIdx.x;
    const int b = bid >> 3, c = bid & 7;
    const int tid = threadIdx.x;
    const int wave = tid >> 6, lane = tid & 63;

    // --- DMA role: wave stages 4 pairs of tensor (wave>>2); pair p = (wave&3)*4 + j ---
    const int tz = wave >> 2;
    const int quad = wave & 3;
    const float* gsrc = tz ? neg : pos;
    const float* gptr[4];
    int dmaoff[4];   // float offset within buffer (wave-uniform)
#pragma unroll
    for (int j = 0; j < 4; ++j) {
        int p = quad * 4 + j;
        int row = 2 * p + (lane >> 5);
        int sw = row & 7;                               // = 2j + (lane>>5)
        int js_src = (lane & 31) ^ sw;                  // swizzled source slot
        gptr[j] = gsrc + ((long)(row * B_ + b)) * T_ + c * 1024 + js_src * 4;
        dmaoff[j] = tz * 4096 + p * 256;
    }

    // --- MFMA role: quadrant (qi,qj) of Gram `mat` (A side = pos always) ---
    const int mat = wave >> 2, qi = (wave >> 1) & 1, qj = wave & 1;
    const int m16 = lane & 15, h2 = lane >> 4;
    const int arow = qi * 16 + m16, brow = qj * 16 + m16;
    const int aoffb = (arow >> 1) * 256 + (arow & 1) * 128;              // tensor 0
    const int boffb = mat * 4096 + (brow >> 1) * 256 + (brow & 1) * 128;
    const int swa = arow & 7, swb = brow & 7;
    const bool statp = (mat == 0) && (qj == 0);   // waves 0,2: pos rows arow
    const bool statn = (mat == 1) && (qi == 0);   // waves 4,5: neg rows brow

    floatx4 acc = {};
    float ssum = 0.f, ssq = 0.f;

#define ISSUE(ch, buf)                                                              \
    do {                                                                            \
        _Pragma("unroll") for (int j = 0; j < 4; ++j) {                             \
            __builtin_amdgcn_global_load_lds(                                       \
                (const __attribute__((address_space(1))) void*)(gptr[j] + (ch)*128),\
                (__attribute__((address_space(3))) void*)(smem + (buf)*BUFF + dmaoff[j]), \
                16, 0, 0);                                                          \
        }                                                                           \
    } while (0)

    ISSUE(0, 0);
    ISSUE(1, 1);

    for (int ch = 0; ch < NCH; ++ch) {
        const int buf = ch & 1;
        if (ch < NCH - 1) {
            asm volatile("s_waitcnt vmcnt(4)" ::: "memory");   // chunk ch landed; ch+1 in flight
        } else {
            asm volatile("s_waitcnt vmcnt(0)" ::: "memory");
        }
        asm volatile("s_barrier" ::: "memory");                // chunk ch visible to all waves

        const float* base = smem + buf * BUFF;
#pragma unroll
        for (int kk = 0; kk < 4; ++kk) {
            const int js = kk * 8 + h2 * 2;
            float4 a0 = *(const float4*)(base + aoffb + ((js ^ swa) << 2));
            float4 a1 = *(const float4*)(base + aoffb + (((js + 1) ^ swa) << 2));
            float4 b0 = *(const float4*)(base + boffb + ((js ^ swb) << 2));
            float4 b1 = *(const float4*)(base + boffb + (((js + 1) ^ swb) << 2));

            if (statp) {
                ssum += a0.x + a0.y + a0.z + a0.w + a1.x + a1.y + a1.z + a1.w;
                ssq = fmaf(a0.x, a0.x, ssq); ssq = fmaf(a0.y, a0.y, ssq);
                ssq = fmaf(a0.z, a0.z, ssq); ssq = fmaf(a0.w, a0.w, ssq);
                ssq = fmaf(a1.x, a1.x, ssq); ssq = fmaf(a1.y, a1.y, ssq);
                ssq = fmaf(a1.z, a1.z, ssq); ssq = fmaf(a1.w, a1.w, ssq);
            }
            if (statn) {
                ssum += b0.x + b0.y + b0.z + b0.w + b1.x + b1.y + b1.z + b1.w;
                ssq = fmaf(b0.x, b0.x, ssq); ssq = fmaf(b0.y, b0.y, ssq);
                ssq = fmaf(b0.z, b0.z, ssq); ssq = fmaf(b0.w, b0.w, ssq);
                ssq = fmaf(b1.x, b1.x, ssq); ssq = fmaf(b1.y, b1.y, ssq);
                ssq = fmaf(b1.z, b1.z, ssq); ssq = fmaf(b1.w, b1.w, ssq);
            }

            // A-operand layout (m120-verified): A[m = lane&15][k = (lane>>4)*8 + j];
            // same layout both sides -> mfma(x,y) = X . Y^T (the Gram).
            half8 af = {(_Float16)a0.x, (_Float16)a0.y, (_Float16)a0.z, (_Float16)a0.w,
                        (_Float16)a1.x, (_Float16)a1.y, (_Float16)a1.z, (_Float16)a1.w};
            half8 bf = {(_Float16)b0.x, (_Float16)b0.y, (_Float16)b0.z, (_Float16)b0.w,
                        (_Float16)b1.x, (_Float16)b1.y, (_Float16)b1.z, (_Float16)b1.w};
            acc = __builtin_amdgcn_mfma_f32_16x16x32_f16(af, bf, acc, 0, 0, 0);
        }

        asm volatile("s_barrier" ::: "memory");   // all reads of `buf` done
        if (ch + 2 < NCH) ISSUE(ch + 2, buf);     // refill while next chunk is consumed
    }
#undef ISSUE

    // fold the 4 h2-slices: lanes m16, 16+m16, 32+m16, 48+m16 share a row
    ssum += __shfl_xor(ssum, 16); ssum += __shfl_xor(ssum, 32);
    ssq += __shfl_xor(ssq, 16); ssq += __shfl_xor(ssq, 32);

    float* out = partial + (long)bid * PSTRIDE;
    if (h2 == 0) {
        if (statp) {                       // pos rows arow = qi*16 + m16
            out[2048 + arow] = ssum;       // sx
            out[2080 + arow] = ssq;        // sx2
        }
        if (statn) {                       // neg rows brow = qj*16 + m16
            out[2112 + brow] = ssum;       // sy
            out[2144 + brow] = ssq;        // sy2
        }
    }

    // C/D layout 16x16 (m89-verified): col = lane&15, row = (lane>>4)*4 + reg
#pragma unroll
    for (int reg = 0; reg < 4; ++reg) {
        int rr = qi * 16 + h2 * 4 + reg;
        int cc = qj * 16 + m16;
        out[mat * 1024 + rr * 32 + cc] = acc[reg];
    }
}

// ---------------- Stage 2: reduce 8 slice partials -> per-b stats ----------------
__global__ void k_reduce(const float* __restrict__ partial, float* __restrict__ red) {
    const int b = blockIdx.y;
    const int o = blockIdx.x * 128 + threadIdx.x;   // 0..2175
    const float* in = partial + (long)b * SLICES * PSTRIDE;
    float s = 0.f;
#pragma unroll
    for (int c = 0; c < SLICES; ++c) s += in[c * PSTRIDE + o];
    red[(long)b * PSTRIDE + o] = s;
}

// ---------------- Stage 3: per-entry pearson over b, exp terms ----------------
__global__ void k_entries(const float* __restrict__ red, double* __restrict__ blocksums) {
    const int tid = threadIdx.x;
    const int w = tid >> 6, lane = tid & 63;
    const int entry = blockIdx.x * 4 + w;
    const int mat = entry >> 10;       // 0 = pp, 1 = pn
    const int idx = entry & 1023;
    const int n = idx >> 5, m = idx & 31;

    const float* rb = red + (long)lane * PSTRIDE;
    float g = rb[mat * 1024 + idx];
    float sxn = rb[2048 + n];
    float sx2n = rb[2080 + n];
    float sym, sy2m;
    if (mat == 0) {
        sym = rb[2048 + m];
        sy2m = rb[2080 + m];
    } else {
        sym = rb[2112 + m];
        sy2m = rb[2144 + m];
    }

    double num = (double)T_ * (double)g - (double)sxn * (double)sym;
    double vx = (double)T_ * (double)sx2n - (double)sxn * (double)sxn;
    double vy = (double)T_ * (double)sy2m - (double)sym * (double)sym;
    double contrib = 1.0 - num / sqrt(vx * vy);

#pragma unroll
    for (int off = 32; off; off >>= 1) contrib += __shfl_down(contrib, off);

    __shared__ double s_pos[4], s_neg[4];
    if (lane == 0) {
        double d = contrib * (1.0 / B_);
        double term = exp(d / 0.08);
        double p = 0.0, q = 0.0;
        if (mat == 0) {
            if (n < m) p = term;     // strict upper triangle only
        } else {
            q = term;
        }
        s_pos[w] = p;
        s_neg[w] = q;
    }
    __syncthreads();
    if (tid == 0) {
        blocksums[blockIdx.x * 2 + 0] = s_pos[0] + s_pos[1] + s_pos[2] + s_pos[3];
        blocksums[blockIdx.x * 2 + 1] = s_neg[0] + s_neg[1] + s_neg[2] + s_neg[3];
    }
}

// ---------------- Stage 4: final scalar ----------------
__global__ void k_final(const double* __restrict__ blocksums, float* __restrict__ out) {
    __shared__ double sp[256], sn[256];
    const int tid = threadIdx.x;
    double p = 0.0, q = 0.0;
    for (int i = tid; i < 512; i += 256) {
        p += blocksums[2 * i + 0];
        q += blocksums[2 * i + 1];
    }
    sp[tid] = p;
    sn[tid] = q;
    __syncthreads();
    for (int s = 128; s; s >>= 1) {
        if (tid < s) {
            sp[tid] += sp[tid + s];
            sn[tid] += sn[tid + s];
        }
        __syncthreads();
    }
    if (tid == 0) out[0] = (float)log10(sp[0] / sn[0] + 1.0);
}

extern "C" void kernel_launch(void* const* d_in, const int* in_sizes, int n_in,
                              void* d_out, int out_size, void* d_ws, size_t ws_size,
                              hipStream_t stream) {
    const float* pos = (const float*)d_in[0];
    const float* neg = (const float*)d_in[1];
    float* out = (float*)d_out;

    char* ws = (char*)d_ws;
    float* partial = (float*)ws;                               // 512*2176*4 = 4,456,448 B
    float* red = (float*)(ws + (size_t)512 * PSTRIDE * 4);     //  64*2176*4 =   557,056 B
    double* blocksums = (double*)(ws + (size_t)512 * PSTRIDE * 4 + (size_t)64 * PSTRIDE * 4);

    k_stage1<<<512, 512, 0, stream>>>(pos, neg, partial);
    k_reduce<<<dim3(17, 64), 128, 0, stream>>>(partial, red);
    k_entries<<<512, 256, 0, stream>>>(red, blocksums);
    k_final<<<1, 256, 0, stream>>>(blocksums, out);
}

// Round 6
// 158.007 us; speedup vs baseline: 1.0568x; 1.0248x over previous
//
#include <hip/hip_runtime.h>
#include <cmath>

#define N_ 32
#define B_ 64
#define T_ 8192
#define SLICES 8                    // 1024-t slices per b
#define NCH 8                       // 128-t chunks per slice
#define PSTRIDE 2176                // 1024 pp + 1024 pn + 4*32 sums
// LDS: double buffer; buffer = 2 tensors x 16 pairs x 256 floats (pair = 2 rows x 128 t).
// Bank safety via XOR swizzle of 16-B t-slots: slot_phys = slot ^ (row & 7).
#define BUFF 8192                   // floats per buffer (32 KB)

typedef _Float16 half8 __attribute__((ext_vector_type(8)));
typedef float floatx4 __attribute__((ext_vector_type(4)));

// ---------------- Stage 1: pipelined DMA -> fp32 LDS -> cvt+MFMA (+reg stats) ----------
// grid 512 = 64 b * 8 slices; block 512 (8 waves); 64 KB LDS -> 2 blocks/CU.
// Pearson is invariant to the reference's per-n affine normalization -> raw data.
// Anti-channel-collision: slice = (c0+b)&7 and chunk order rotated by (3b+5c0)&7 so
// concurrent blocks/chunks cover address bits 9-14 instead of piling on one phase.
__global__ __launch_bounds__(512, 4) void k_stage1(const float* __restrict__ pos,
                                                   const float* __restrict__ neg,
                                                   float* __restrict__ partial) {
    __shared__ __align__(16) float smem[2 * BUFF];   // 65536 B

    const int bid = blockIdx.x;
    const int b = bid >> 3, c0 = bid & 7;
    const int c = (c0 + b) & 7;                 // slice rotation (bijective per b)
    const int rot = (3 * b + 5 * c0) & 7;       // chunk-order rotation
    const int tid = threadIdx.x;
    const int wave = tid >> 6, lane = tid & 63;

    // --- DMA role: wave stages 4 pairs of tensor (wave>>2); pair p = (wave&3)*4 + j ---
    const int tz = wave >> 2;
    const int quad = wave & 3;
    const float* gsrc = tz ? neg : pos;
    const float* gptr[4];
    int dmaoff[4];   // float offset within buffer (wave-uniform)
#pragma unroll
    for (int j = 0; j < 4; ++j) {
        int p = quad * 4 + j;
        int row = 2 * p + (lane >> 5);
        int sw = row & 7;
        int js_src = (lane & 31) ^ sw;                  // swizzled source slot
        gptr[j] = gsrc + ((long)(row * B_ + b)) * T_ + c * 1024 + js_src * 4;
        dmaoff[j] = tz * 4096 + p * 256;
    }

    // --- MFMA role: quadrant (qi,qj) of Gram `mat` (A side = pos always) ---
    const int mat = wave >> 2, qi = (wave >> 1) & 1, qj = wave & 1;
    const int m16 = lane & 15, h2 = lane >> 4;
    const int arow = qi * 16 + m16, brow = qj * 16 + m16;
    const int aoffb = (arow >> 1) * 256 + (arow & 1) * 128;              // tensor 0
    const int boffb = mat * 4096 + (brow >> 1) * 256 + (brow & 1) * 128;
    const int swa = arow & 7, swb = brow & 7;
    const bool statp = (mat == 0) && (qj == 0);   // waves 0,2: pos rows arow
    const bool statn = (mat == 1) && (qi == 0);   // waves 4,5: neg rows brow

    floatx4 acc = {};
    float ssum = 0.f, ssq = 0.f;

#define CIDX(i) ((((i) + rot) & 7) * 128)
#define ISSUE(i, buf)                                                               \
    do {                                                                            \
        _Pragma("unroll") for (int j = 0; j < 4; ++j) {                             \
            __builtin_amdgcn_global_load_lds(                                       \
                (const __attribute__((address_space(1))) void*)(gptr[j] + CIDX(i)), \
                (__attribute__((address_space(3))) void*)(smem + (buf)*BUFF + dmaoff[j]), \
                16, 0, 0);                                                          \
        }                                                                           \
    } while (0)

    ISSUE(0, 0);
    ISSUE(1, 1);

    for (int ch = 0; ch < NCH; ++ch) {
        const int buf = ch & 1;
        if (ch < NCH - 1) {
            asm volatile("s_waitcnt vmcnt(4)" ::: "memory");   // chunk ch landed; ch+1 in flight
        } else {
            asm volatile("s_waitcnt vmcnt(0)" ::: "memory");
        }
        asm volatile("s_barrier" ::: "memory");                // chunk ch visible to all waves

        const float* base = smem + buf * BUFF;
#pragma unroll
        for (int kk = 0; kk < 4; ++kk) {
            const int js = kk * 8 + h2 * 2;
            float4 a0 = *(const float4*)(base + aoffb + ((js ^ swa) << 2));
            float4 a1 = *(const float4*)(base + aoffb + (((js + 1) ^ swa) << 2));
            float4 b0 = *(const float4*)(base + boffb + ((js ^ swb) << 2));
            float4 b1 = *(const float4*)(base + boffb + (((js + 1) ^ swb) << 2));

            if (statp) {
                ssum += a0.x + a0.y + a0.z + a0.w + a1.x + a1.y + a1.z + a1.w;
                ssq = fmaf(a0.x, a0.x, ssq); ssq = fmaf(a0.y, a0.y, ssq);
                ssq = fmaf(a0.z, a0.z, ssq); ssq = fmaf(a0.w, a0.w, ssq);
                ssq = fmaf(a1.x, a1.x, ssq); ssq = fmaf(a1.y, a1.y, ssq);
                ssq = fmaf(a1.z, a1.z, ssq); ssq = fmaf(a1.w, a1.w, ssq);
            }
            if (statn) {
                ssum += b0.x + b0.y + b0.z + b0.w + b1.x + b1.y + b1.z + b1.w;
                ssq = fmaf(b0.x, b0.x, ssq); ssq = fmaf(b0.y, b0.y, ssq);
                ssq = fmaf(b0.z, b0.z, ssq); ssq = fmaf(b0.w, b0.w, ssq);
                ssq = fmaf(b1.x, b1.x, ssq); ssq = fmaf(b1.y, b1.y, ssq);
                ssq = fmaf(b1.z, b1.z, ssq); ssq = fmaf(b1.w, b1.w, ssq);
            }

            // A-operand layout (m120-verified): A[m = lane&15][k = (lane>>4)*8 + j];
            // same layout both sides -> mfma(x,y) = X . Y^T (the Gram).
            half8 af = {(_Float16)a0.x, (_Float16)a0.y, (_Float16)a0.z, (_Float16)a0.w,
                        (_Float16)a1.x, (_Float16)a1.y, (_Float16)a1.z, (_Float16)a1.w};
            half8 bf = {(_Float16)b0.x, (_Float16)b0.y, (_Float16)b0.z, (_Float16)b0.w,
                        (_Float16)b1.x, (_Float16)b1.y, (_Float16)b1.z, (_Float16)b1.w};
            acc = __builtin_amdgcn_mfma_f32_16x16x32_f16(af, bf, acc, 0, 0, 0);
        }

        asm volatile("s_barrier" ::: "memory");   // all reads of `buf` done
        if (ch + 2 < NCH) ISSUE(ch + 2, buf);     // refill while next chunk is consumed
    }
#undef ISSUE
#undef CIDX

    // fold the 4 h2-slices: lanes m16, 16+m16, 32+m16, 48+m16 share a row
    ssum += __shfl_xor(ssum, 16); ssum += __shfl_xor(ssum, 32);
    ssq += __shfl_xor(ssq, 16); ssq += __shfl_xor(ssq, 32);

    float* out = partial + (long)bid * PSTRIDE;
    if (h2 == 0) {
        if (statp) {                       // pos rows arow = qi*16 + m16
            out[2048 + arow] = ssum;       // sx
            out[2080 + arow] = ssq;        // sx2
        }
        if (statn) {                       // neg rows brow = qj*16 + m16
            out[2112 + brow] = ssum;       // sy
            out[2144 + brow] = ssq;        // sy2
        }
    }

    // C/D layout 16x16 (m89-verified): col = lane&15, row = (lane>>4)*4 + reg
#pragma unroll
    for (int reg = 0; reg < 4; ++reg) {
        int rr = qi * 16 + h2 * 4 + reg;
        int cc = qj * 16 + m16;
        out[mat * 1024 + rr * 32 + cc] = acc[reg];
    }
}

// ---------------- Stage 2: reduce 8 slice partials -> per-b stats ----------------
__global__ void k_reduce(const float* __restrict__ partial, float* __restrict__ red) {
    const int b = blockIdx.y;
    const int o = blockIdx.x * 128 + threadIdx.x;   // 0..2175
    const float* in = partial + (long)b * SLICES * PSTRIDE;
    float s = 0.f;
#pragma unroll
    for (int c = 0; c < SLICES; ++c) s += in[c * PSTRIDE + o];
    red[(long)b * PSTRIDE + o] = s;
}

// ---------------- Stage 3: per-entry pearson over b, exp terms ----------------
__global__ void k_entries(const float* __restrict__ red, double* __restrict__ blocksums) {
    const int tid = threadIdx.x;
    const int w = tid >> 6, lane = tid & 63;
    const int entry = blockIdx.x * 4 + w;
    const int mat = entry >> 10;       // 0 = pp, 1 = pn
    const int idx = entry & 1023;
    const int n = idx >> 5, m = idx & 31;

    const float* rb = red + (long)lane * PSTRIDE;
    float g = rb[mat * 1024 + idx];
    float sxn = rb[2048 + n];
    float sx2n = rb[2080 + n];
    float sym, sy2m;
    if (mat == 0) {
        sym = rb[2048 + m];
        sy2m = rb[2080 + m];
    } else {
        sym = rb[2112 + m];
        sy2m = rb[2144 + m];
    }

    double num = (double)T_ * (double)g - (double)sxn * (double)sym;
    double vx = (double)T_ * (double)sx2n - (double)sxn * (double)sxn;
    double vy = (double)T_ * (double)sy2m - (double)sym * (double)sym;
    double contrib = 1.0 - num / sqrt(vx * vy);

#pragma unroll
    for (int off = 32; off; off >>= 1) contrib += __shfl_down(contrib, off);

    __shared__ double s_pos[4], s_neg[4];
    if (lane == 0) {
        double d = contrib * (1.0 / B_);
        double term = exp(d / 0.08);
        double p = 0.0, q = 0.0;
        if (mat == 0) {
            if (n < m) p = term;     // strict upper triangle only
        } else {
            q = term;
        }
        s_pos[w] = p;
        s_neg[w] = q;
    }
    __syncthreads();
    if (tid == 0) {
        blocksums[blockIdx.x * 2 + 0] = s_pos[0] + s_pos[1] + s_pos[2] + s_pos[3];
        blocksums[blockIdx.x * 2 + 1] = s_neg[0] + s_neg[1] + s_neg[2] + s_neg[3];
    }
}

// ---------------- Stage 4: final scalar ----------------
__global__ void k_final(const double* __restrict__ blocksums, float* __restrict__ out) {
    __shared__ double sp[256], sn[256];
    const int tid = threadIdx.x;
    double p = 0.0, q = 0.0;
    for (int i = tid; i < 512; i += 256) {
        p += blocksums[2 * i + 0];
        q += blocksums[2 * i + 1];
    }
    sp[tid] = p;
    sn[tid] = q;
    __syncthreads();
    for (int s = 128; s; s >>= 1) {
        if (tid < s) {
            sp[tid] += sp[tid + s];
            sn[tid] += sn[tid + s];
        }
        __syncthreads();
    }
    if (tid == 0) out[0] = (float)log10(sp[0] / sn[0] + 1.0);
}

extern "C" void kernel_launch(void* const* d_in, const int* in_sizes, int n_in,
                              void* d_out, int out_size, void* d_ws, size_t ws_size,
                              hipStream_t stream) {
    const float* pos = (const float*)d_in[0];
    const float* neg = (const float*)d_in[1];
    float* out = (float*)d_out;

    char* ws = (char*)d_ws;
    float* partial = (float*)ws;                               // 512*2176*4 = 4,456,448 B
    float* red = (float*)(ws + (size_t)512 * PSTRIDE * 4);     //  64*2176*4 =   557,056 B
    double* blocksums = (double*)(ws + (size_t)512 * PSTRIDE * 4 + (size_t)64 * PSTRIDE * 4);

    k_stage1<<<512, 512, 0, stream>>>(pos, neg, partial);
    k_reduce<<<dim3(17, 64), 128, 0, stream>>>(partial, red);
    k_entries<<<512, 256, 0, stream>>>(red, blocksums);
    k_final<<<1, 256, 0, stream>>>(blocksums, out);
}